// Round 5
// baseline (262.948 us; speedup 1.0000x reference)
//
#include <hip/hip_runtime.h>

#define NB 4096
#define HIST 200
#define NNEG 20
#define DIM 64
#define BATA 1e-4f
#define LAMDA 1e-4f

// one BLOCK (4 waves) per user; 16 (wave,group) units x 12 rows + 8-row tail.
// Partial losses -> d_ws; the LAST block (device-scope counter) sums all 4096
// partials in fixed order -> out[0]. Single kernel launch, no atomicAdd on out.
__global__ __launch_bounds__(256) void fism_kernel(
    const int* __restrict__ pos_items,
    const int* __restrict__ neg_items,
    const float* __restrict__ user_item_num,
    const int* __restrict__ interacted,
    const float* __restrict__ pu,
    const float* __restrict__ qi,
    const float* __restrict__ bi,
    float* __restrict__ partials,
    unsigned int* __restrict__ counter,
    float* __restrict__ out)
{
    const int wave = threadIdx.x >> 6;   // 0..3
    const int lane = threadIdx.x & 63;
    const int g    = lane >> 4;          // row-group within wave, 0..3
    const int c    = lane & 15;          // float4 column within a 64-f32 row
    const int gid  = wave * 4 + g;       // 0..15 global group id
    const int b    = blockIdx.x;

    __shared__ float4 s_u[4][16];
    __shared__ float  s_dot[24];
    __shared__ float  s_qsq[24];
    __shared__ int    s_last;
    __shared__ float  s_r[4];

    const float4* pu4 = (const float4*)pu;
    const float4* qi4 = (const float4*)qi;
    const int*    it  = interacted + b * HIST;
    const int*    negp = neg_items + b * NNEG;

    // ---- preload everything whose latency can hide under the pu gather ----
    const int posi = pos_items[b];

    const int4* it4 = (const int4*)(it + gid * 12);
    int4 i0 = it4[0], i1 = it4[1], i2 = it4[2];
    int  tidx = it[192 + (gid & 7)];     // rows 192..199 (used by gid<8)

    const int item0 = (gid == 0) ? posi : negp[gid - 1];
    float4 q0 = qi4[item0 * (DIM / 4) + c];
    float4 q1 = make_float4(0.f, 0.f, 0.f, 0.f);
    if (gid < 5) {                       // j1 = gid+16 in [16,20]
        int item1 = negp[gid + 15];
        q1 = qi4[item1 * (DIM / 4) + c];
    }

    float t_pow = 0.f, bp = 0.f, bn = 0.f;
    if (wave == 0) {
        t_pow = user_item_num[b];
        bp = bi[posi];
        if (lane < NNEG) bn = bi[negp[lane]];
    }

    // ---- user embedding: 13 independent row gathers, 2 accumulator chains --
    float4 a0 = make_float4(0.f, 0.f, 0.f, 0.f);
    float4 a1 = make_float4(0.f, 0.f, 0.f, 0.f);
    {
        float4 v0  = pu4[i0.x * (DIM / 4) + c];
        float4 v1  = pu4[i0.y * (DIM / 4) + c];
        float4 v2  = pu4[i0.z * (DIM / 4) + c];
        float4 v3  = pu4[i0.w * (DIM / 4) + c];
        float4 v4  = pu4[i1.x * (DIM / 4) + c];
        float4 v5  = pu4[i1.y * (DIM / 4) + c];
        float4 v6  = pu4[i1.z * (DIM / 4) + c];
        float4 v7  = pu4[i1.w * (DIM / 4) + c];
        float4 v8  = pu4[i2.x * (DIM / 4) + c];
        float4 v9  = pu4[i2.y * (DIM / 4) + c];
        float4 v10 = pu4[i2.z * (DIM / 4) + c];
        float4 v11 = pu4[i2.w * (DIM / 4) + c];
        float4 vt  = pu4[tidx * (DIM / 4) + c];

        a0.x += v0.x + v1.x; a0.y += v0.y + v1.y; a0.z += v0.z + v1.z; a0.w += v0.w + v1.w;
        a1.x += v2.x + v3.x; a1.y += v2.y + v3.y; a1.z += v2.z + v3.z; a1.w += v2.w + v3.w;
        a0.x += v4.x + v5.x; a0.y += v4.y + v5.y; a0.z += v4.z + v5.z; a0.w += v4.w + v5.w;
        a1.x += v6.x + v7.x; a1.y += v6.y + v7.y; a1.z += v6.z + v7.z; a1.w += v6.w + v7.w;
        a0.x += v8.x + v9.x; a0.y += v8.y + v9.y; a0.z += v8.z + v9.z; a0.w += v8.w + v9.w;
        a1.x += v10.x + v11.x; a1.y += v10.y + v11.y; a1.z += v10.z + v11.z; a1.w += v10.w + v11.w;
        if (gid < 8) {
            a0.x += vt.x; a0.y += vt.y; a0.z += vt.z; a0.w += vt.w;
        }
    }
    float4 u = make_float4(a0.x + a1.x, a0.y + a1.y, a0.z + a1.z, a0.w + a1.w);

    // fold the 4 groups within this wave (lanes sharing c hold same dims)
    #pragma unroll
    for (int m = 16; m <= 32; m <<= 1) {
        u.x += __shfl_xor(u.x, m);
        u.y += __shfl_xor(u.y, m);
        u.z += __shfl_xor(u.z, m);
        u.w += __shfl_xor(u.w, m);
    }
    if (lane < 16) s_u[wave][lane] = u;
    __syncthreads();

    // total user embedding, dims [4c, 4c+3]
    float4 u0 = s_u[0][c], u1 = s_u[1][c], u2 = s_u[2][c], u3 = s_u[3][c];
    float4 ut = make_float4(u0.x + u1.x + u2.x + u3.x,
                            u0.y + u1.y + u2.y + u3.y,
                            u0.z + u1.z + u2.z + u3.z,
                            u0.w + u1.w + u2.w + u3.w);

    float contrib = 0.f;
    if (wave == 0 && g == 0)   // 16 lanes cover the 16 columns exactly once
        contrib += BATA * (ut.x*ut.x + ut.y*ut.y + ut.z*ut.z + ut.w*ut.w);

    // ---- dots with preloaded qi fragments ----
    {
        float dp = ut.x*q0.x + ut.y*q0.y + ut.z*q0.z + ut.w*q0.w;
        float qs = q0.x*q0.x + q0.y*q0.y + q0.z*q0.z + q0.w*q0.w;
        #pragma unroll
        for (int m = 1; m <= 8; m <<= 1) {
            dp += __shfl_xor(dp, m);
            qs += __shfl_xor(qs, m);
        }
        if (c == 0) { s_dot[gid] = dp; s_qsq[gid] = qs; }
    }
    if (gid < 5) {
        float dp = ut.x*q1.x + ut.y*q1.y + ut.z*q1.z + ut.w*q1.w;
        float qs = q1.x*q1.x + q1.y*q1.y + q1.z*q1.z + q1.w*q1.w;
        #pragma unroll
        for (int m = 1; m <= 8; m <<= 1) {
            dp += __shfl_xor(dp, m);
            qs += __shfl_xor(qs, m);
        }
        if (c == 0) { s_dot[gid + 16] = dp; s_qsq[gid + 16] = qs; }
    }
    __syncthreads();

    // ---- scores + loss terms (wave 0 only); partial -> d_ws ----
    if (wave == 0) {
        const float t = 1.0f / sqrtf(t_pow);     // num^(-0.5)
        const float pos_score = t * s_dot[0] + bp;

        if (lane < NNEG) {
            float neg_score = t * s_dot[lane + 1] + bn;
            float d = 1.0f - pos_score + neg_score;
            contrib += d * d + LAMDA * bn * bn + BATA * s_qsq[lane + 1];
        }
        if (lane == 0)
            contrib += LAMDA * bp * bp + BATA * s_qsq[0];

        #pragma unroll
        for (int m = 1; m < 64; m <<= 1)
            contrib += __shfl_xor(contrib, m);
        if (lane == 0)
            __hip_atomic_store(&partials[b], contrib,
                               __ATOMIC_RELEASE, __HIP_MEMORY_SCOPE_AGENT);
    }

    // ---- last-block-done final reduction (deterministic fixed order) ----
    if (threadIdx.x == 0) {
        unsigned int old = __hip_atomic_fetch_add(counter, 1u,
                               __ATOMIC_ACQ_REL, __HIP_MEMORY_SCOPE_AGENT);
        s_last = (old == NB - 1);
    }
    __syncthreads();
    if (s_last) {
        float v = 0.f;
        #pragma unroll
        for (int k = 0; k < NB / 256; ++k)   // 16 device-scope loads, fixed order
            v += __hip_atomic_load(&partials[threadIdx.x * (NB / 256) + k],
                                   __ATOMIC_RELAXED, __HIP_MEMORY_SCOPE_AGENT);
        #pragma unroll
        for (int m = 1; m < 64; m <<= 1)
            v += __shfl_xor(v, m);
        if (lane == 0) s_r[wave] = v;
        __syncthreads();
        if (threadIdx.x == 0)
            out[0] = s_r[0] + s_r[1] + s_r[2] + s_r[3];
    }
}

extern "C" void kernel_launch(void* const* d_in, const int* in_sizes, int n_in,
                              void* d_out, int out_size, void* d_ws, size_t ws_size,
                              hipStream_t stream) {
    const int*   pos_items     = (const int*)  d_in[0];
    const int*   neg_items     = (const int*)  d_in[1];
    const float* user_item_num = (const float*)d_in[2];
    const int*   interacted    = (const int*)  d_in[3];
    const float* pu            = (const float*)d_in[4];
    const float* qi            = (const float*)d_in[5];
    const float* bi            = (const float*)d_in[6];
    float*        partials = (float*)d_ws;                 // NB floats
    unsigned int* counter  = (unsigned int*)((char*)d_ws + NB * sizeof(float));
    float* out = (float*)d_out;

    hipMemsetAsync(counter, 0, sizeof(unsigned int), stream);  // re-zeroed every replay
    fism_kernel<<<NB, 256, 0, stream>>>(
        pos_items, neg_items, user_item_num, interacted, pu, qi, bi,
        partials, counter, out);
}

// Round 6
// 48.777 us; speedup vs baseline: 5.3908x; 5.3908x over previous
//
#include <hip/hip_runtime.h>

#define NB 4096
#define UPB 8                 // users per block
#define NBLK (NB / UPB)       // 512 blocks
#define HIST 200
#define NNEG 20
#define DIM 64
#define BATA 1e-4f
#define LAMDA 1e-4f

// one BLOCK (4 waves) processes UPB users sequentially; 16 (wave,group) units
// x 12 rows + 8-row tail per user. One relaxed atomicAdd per block (512 total).
__global__ __launch_bounds__(256) void fism_kernel(
    const int* __restrict__ pos_items,
    const int* __restrict__ neg_items,
    const float* __restrict__ user_item_num,
    const int* __restrict__ interacted,
    const float* __restrict__ pu,
    const float* __restrict__ qi,
    const float* __restrict__ bi,
    float* __restrict__ out)
{
    const int wave = threadIdx.x >> 6;   // 0..3
    const int lane = threadIdx.x & 63;
    const int g    = lane >> 4;          // row-group within wave, 0..3
    const int c    = lane & 15;          // float4 column within a 64-f32 row
    const int gid  = wave * 4 + g;       // 0..15 global group id

    __shared__ float4 s_u[4][16];
    __shared__ float  s_dot[24];
    __shared__ float  s_qsq[24];

    const float4* pu4 = (const float4*)pu;
    const float4* qi4 = (const float4*)qi;

    float blockAcc = 0.f;                // meaningful on wave 0 lane 0

    for (int uu = 0; uu < UPB; ++uu) {
        const int b = blockIdx.x * UPB + uu;
        const int* it   = interacted + b * HIST;
        const int* negp = neg_items + b * NNEG;

        // ---- preload: indices, qi fragments, biases ----
        const int posi = pos_items[b];

        const int4* it4 = (const int4*)(it + gid * 12);
        int4 i0 = it4[0], i1 = it4[1], i2 = it4[2];
        int  tidx = it[192 + (gid & 7)];       // rows 192..199 (used by gid<8)

        const int item0 = (gid == 0) ? posi : negp[gid - 1];
        float4 q0 = qi4[item0 * (DIM / 4) + c];
        float4 q1 = make_float4(0.f, 0.f, 0.f, 0.f);
        if (gid < 5) {                          // j1 = gid+16 in [16,20]
            int item1 = negp[gid + 15];
            q1 = qi4[item1 * (DIM / 4) + c];
        }

        float t_pow = 0.f, bp = 0.f, bn = 0.f;
        if (wave == 0) {
            t_pow = user_item_num[b];
            bp = bi[posi];
            if (lane < NNEG) bn = bi[negp[lane]];
        }

        // ---- user embedding: 13 independent row gathers, 2 acc chains ----
        float4 a0 = make_float4(0.f, 0.f, 0.f, 0.f);
        float4 a1 = make_float4(0.f, 0.f, 0.f, 0.f);
        {
            float4 v0  = pu4[i0.x * (DIM / 4) + c];
            float4 v1  = pu4[i0.y * (DIM / 4) + c];
            float4 v2  = pu4[i0.z * (DIM / 4) + c];
            float4 v3  = pu4[i0.w * (DIM / 4) + c];
            float4 v4  = pu4[i1.x * (DIM / 4) + c];
            float4 v5  = pu4[i1.y * (DIM / 4) + c];
            float4 v6  = pu4[i1.z * (DIM / 4) + c];
            float4 v7  = pu4[i1.w * (DIM / 4) + c];
            float4 v8  = pu4[i2.x * (DIM / 4) + c];
            float4 v9  = pu4[i2.y * (DIM / 4) + c];
            float4 v10 = pu4[i2.z * (DIM / 4) + c];
            float4 v11 = pu4[i2.w * (DIM / 4) + c];
            float4 vt  = pu4[tidx * (DIM / 4) + c];

            a0.x += v0.x + v1.x; a0.y += v0.y + v1.y; a0.z += v0.z + v1.z; a0.w += v0.w + v1.w;
            a1.x += v2.x + v3.x; a1.y += v2.y + v3.y; a1.z += v2.z + v3.z; a1.w += v2.w + v3.w;
            a0.x += v4.x + v5.x; a0.y += v4.y + v5.y; a0.z += v4.z + v5.z; a0.w += v4.w + v5.w;
            a1.x += v6.x + v7.x; a1.y += v6.y + v7.y; a1.z += v6.z + v7.z; a1.w += v6.w + v7.w;
            a0.x += v8.x + v9.x; a0.y += v8.y + v9.y; a0.z += v8.z + v9.z; a0.w += v8.w + v9.w;
            a1.x += v10.x + v11.x; a1.y += v10.y + v11.y; a1.z += v10.z + v11.z; a1.w += v10.w + v11.w;
            if (gid < 8) {
                a0.x += vt.x; a0.y += vt.y; a0.z += vt.z; a0.w += vt.w;
            }
        }
        float4 u = make_float4(a0.x + a1.x, a0.y + a1.y, a0.z + a1.z, a0.w + a1.w);

        // fold the 4 groups within this wave
        #pragma unroll
        for (int m = 16; m <= 32; m <<= 1) {
            u.x += __shfl_xor(u.x, m);
            u.y += __shfl_xor(u.y, m);
            u.z += __shfl_xor(u.z, m);
            u.w += __shfl_xor(u.w, m);
        }
        if (lane < 16) s_u[wave][lane] = u;
        __syncthreads();                                   // sync #1

        float4 u0 = s_u[0][c], u1 = s_u[1][c], u2 = s_u[2][c], u3 = s_u[3][c];
        float4 ut = make_float4(u0.x + u1.x + u2.x + u3.x,
                                u0.y + u1.y + u2.y + u3.y,
                                u0.z + u1.z + u2.z + u3.z,
                                u0.w + u1.w + u2.w + u3.w);

        float contrib = 0.f;
        if (wave == 0 && g == 0)   // 16 lanes cover the 16 columns once
            contrib += BATA * (ut.x*ut.x + ut.y*ut.y + ut.z*ut.z + ut.w*ut.w);

        // ---- dots with preloaded qi fragments ----
        {
            float dp = ut.x*q0.x + ut.y*q0.y + ut.z*q0.z + ut.w*q0.w;
            float qs = q0.x*q0.x + q0.y*q0.y + q0.z*q0.z + q0.w*q0.w;
            #pragma unroll
            for (int m = 1; m <= 8; m <<= 1) {
                dp += __shfl_xor(dp, m);
                qs += __shfl_xor(qs, m);
            }
            if (c == 0) { s_dot[gid] = dp; s_qsq[gid] = qs; }
        }
        if (gid < 5) {
            float dp = ut.x*q1.x + ut.y*q1.y + ut.z*q1.z + ut.w*q1.w;
            float qs = q1.x*q1.x + q1.y*q1.y + q1.z*q1.z + q1.w*q1.w;
            #pragma unroll
            for (int m = 1; m <= 8; m <<= 1) {
                dp += __shfl_xor(dp, m);
                qs += __shfl_xor(qs, m);
            }
            if (c == 0) { s_dot[gid + 16] = dp; s_qsq[gid + 16] = qs; }
        }
        __syncthreads();                                   // sync #2

        // ---- scores + loss terms (wave 0 only) ----
        // Race-safety across iterations: wave0 reads s_dot/s_qsq here, BEFORE
        // it reaches the next iteration's sync #1; other waves' next writes to
        // s_dot happen only AFTER that sync. No extra barrier needed.
        if (wave == 0) {
            const float t = 1.0f / sqrtf(t_pow);           // num^(-0.5)
            const float pos_score = t * s_dot[0] + bp;

            if (lane < NNEG) {
                float neg_score = t * s_dot[lane + 1] + bn;
                float d = 1.0f - pos_score + neg_score;
                contrib += d * d + LAMDA * bn * bn + BATA * s_qsq[lane + 1];
            }
            if (lane == 0)
                contrib += LAMDA * bp * bp + BATA * s_qsq[0];

            #pragma unroll
            for (int m = 1; m < 64; m <<= 1)
                contrib += __shfl_xor(contrib, m);
            blockAcc += contrib;                           // lane 0 holds sum
        }
    }

    if (wave == 0 && lane == 0)
        atomicAdd(out, blockAcc);          // 512 relaxed RMWs total
}

extern "C" void kernel_launch(void* const* d_in, const int* in_sizes, int n_in,
                              void* d_out, int out_size, void* d_ws, size_t ws_size,
                              hipStream_t stream) {
    const int*   pos_items     = (const int*)  d_in[0];
    const int*   neg_items     = (const int*)  d_in[1];
    const float* user_item_num = (const float*)d_in[2];
    const int*   interacted    = (const int*)  d_in[3];
    const float* pu            = (const float*)d_in[4];
    const float* qi            = (const float*)d_in[5];
    const float* bi            = (const float*)d_in[6];
    float* out = (float*)d_out;

    hipMemsetAsync(out, 0, sizeof(float), stream);   // atomics accumulate
    fism_kernel<<<NBLK, 256, 0, stream>>>(
        pos_items, neg_items, user_item_num, interacted, pu, qi, bi, out);
}

// Round 7
// 43.915 us; speedup vs baseline: 5.9877x; 1.1107x over previous
//
#include <hip/hip_runtime.h>

#define NB 4096
#define HIST 200
#define NNEG 20
#define DIM 64
#define BATA 1e-4f
#define LAMDA 1e-4f

#define NBUCKET 64
// d_ws layout (all zeroed by memset each replay):
//   [i*64]        float bucket[i]   (64 buckets, one per 64B line)
//   [4096 + i*64] uint  sub[i]      (64 sub-counters, one per line)
//   [8192]        uint  super
#define WS_SUB_OFF   4096
#define WS_SUPER_OFF 8192
#define WS_ZERO_BYTES 8256

// one BLOCK (4 waves) per user; 16 (wave,group) units x 12 rows + 8-row tail.
// Loss partial -> bucket[blockIdx&63] via relaxed atomicAdd; hierarchical
// relaxed counters elect the globally-last block, which sums the 64 buckets
// in fixed order -> out[0]. No fences, no second kernel.
__global__ __launch_bounds__(256) void fism_kernel(
    const int* __restrict__ pos_items,
    const int* __restrict__ neg_items,
    const float* __restrict__ user_item_num,
    const int* __restrict__ interacted,
    const float* __restrict__ pu,
    const float* __restrict__ qi,
    const float* __restrict__ bi,
    char* __restrict__ ws,
    float* __restrict__ out)
{
    const int wave = threadIdx.x >> 6;   // 0..3
    const int lane = threadIdx.x & 63;
    const int g    = lane >> 4;          // row-group within wave, 0..3
    const int c    = lane & 15;          // float4 column within a 64-f32 row
    const int gid  = wave * 4 + g;       // 0..15 global group id
    const int b    = blockIdx.x;

    __shared__ float4 s_u[4][16];
    __shared__ float  s_dot[24];
    __shared__ float  s_qsq[24];
    __shared__ int    s_won;

    const float4* pu4 = (const float4*)pu;
    const float4* qi4 = (const float4*)qi;
    const int*    it  = interacted + b * HIST;
    const int*    negp = neg_items + b * NNEG;

    // ---- preload: indices, qi fragments, biases ----
    const int posi = pos_items[b];

    const int4* it4 = (const int4*)(it + gid * 12);
    int4 i0 = it4[0], i1 = it4[1], i2 = it4[2];
    int  tidx = it[192 + (gid & 7)];     // rows 192..199 (used by gid<8)

    const int item0 = (gid == 0) ? posi : negp[gid - 1];
    float4 q0 = qi4[item0 * (DIM / 4) + c];
    float4 q1 = make_float4(0.f, 0.f, 0.f, 0.f);
    if (gid < 5) {                       // j1 = gid+16 in [16,20]
        int item1 = negp[gid + 15];
        q1 = qi4[item1 * (DIM / 4) + c];
    }

    float t_pow = 0.f, bp = 0.f, bn = 0.f;
    if (wave == 0) {
        t_pow = user_item_num[b];
        bp = bi[posi];
        if (lane < NNEG) bn = bi[negp[lane]];
    }

    // ---- user embedding: 13 independent row gathers, 2 accumulator chains --
    float4 a0 = make_float4(0.f, 0.f, 0.f, 0.f);
    float4 a1 = make_float4(0.f, 0.f, 0.f, 0.f);
    {
        float4 v0  = pu4[i0.x * (DIM / 4) + c];
        float4 v1  = pu4[i0.y * (DIM / 4) + c];
        float4 v2  = pu4[i0.z * (DIM / 4) + c];
        float4 v3  = pu4[i0.w * (DIM / 4) + c];
        float4 v4  = pu4[i1.x * (DIM / 4) + c];
        float4 v5  = pu4[i1.y * (DIM / 4) + c];
        float4 v6  = pu4[i1.z * (DIM / 4) + c];
        float4 v7  = pu4[i1.w * (DIM / 4) + c];
        float4 v8  = pu4[i2.x * (DIM / 4) + c];
        float4 v9  = pu4[i2.y * (DIM / 4) + c];
        float4 v10 = pu4[i2.z * (DIM / 4) + c];
        float4 v11 = pu4[i2.w * (DIM / 4) + c];
        float4 vt  = pu4[tidx * (DIM / 4) + c];

        a0.x += v0.x + v1.x; a0.y += v0.y + v1.y; a0.z += v0.z + v1.z; a0.w += v0.w + v1.w;
        a1.x += v2.x + v3.x; a1.y += v2.y + v3.y; a1.z += v2.z + v3.z; a1.w += v2.w + v3.w;
        a0.x += v4.x + v5.x; a0.y += v4.y + v5.y; a0.z += v4.z + v5.z; a0.w += v4.w + v5.w;
        a1.x += v6.x + v7.x; a1.y += v6.y + v7.y; a1.z += v6.z + v7.z; a1.w += v6.w + v7.w;
        a0.x += v8.x + v9.x; a0.y += v8.y + v9.y; a0.z += v8.z + v9.z; a0.w += v8.w + v9.w;
        a1.x += v10.x + v11.x; a1.y += v10.y + v11.y; a1.z += v10.z + v11.z; a1.w += v10.w + v11.w;
        if (gid < 8) {
            a0.x += vt.x; a0.y += vt.y; a0.z += vt.z; a0.w += vt.w;
        }
    }
    float4 u = make_float4(a0.x + a1.x, a0.y + a1.y, a0.z + a1.z, a0.w + a1.w);

    // fold the 4 groups within this wave (lanes sharing c hold same dims)
    #pragma unroll
    for (int m = 16; m <= 32; m <<= 1) {
        u.x += __shfl_xor(u.x, m);
        u.y += __shfl_xor(u.y, m);
        u.z += __shfl_xor(u.z, m);
        u.w += __shfl_xor(u.w, m);
    }
    if (lane < 16) s_u[wave][lane] = u;
    __syncthreads();

    // total user embedding, dims [4c, 4c+3]
    float4 u0 = s_u[0][c], u1 = s_u[1][c], u2 = s_u[2][c], u3 = s_u[3][c];
    float4 ut = make_float4(u0.x + u1.x + u2.x + u3.x,
                            u0.y + u1.y + u2.y + u3.y,
                            u0.z + u1.z + u2.z + u3.z,
                            u0.w + u1.w + u2.w + u3.w);

    float contrib = 0.f;
    if (wave == 0 && g == 0)   // 16 lanes cover the 16 columns exactly once
        contrib += BATA * (ut.x*ut.x + ut.y*ut.y + ut.z*ut.z + ut.w*ut.w);

    // ---- dots with preloaded qi fragments ----
    {
        float dp = ut.x*q0.x + ut.y*q0.y + ut.z*q0.z + ut.w*q0.w;
        float qs = q0.x*q0.x + q0.y*q0.y + q0.z*q0.z + q0.w*q0.w;
        #pragma unroll
        for (int m = 1; m <= 8; m <<= 1) {
            dp += __shfl_xor(dp, m);
            qs += __shfl_xor(qs, m);
        }
        if (c == 0) { s_dot[gid] = dp; s_qsq[gid] = qs; }
    }
    if (gid < 5) {
        float dp = ut.x*q1.x + ut.y*q1.y + ut.z*q1.z + ut.w*q1.w;
        float qs = q1.x*q1.x + q1.y*q1.y + q1.z*q1.z + q1.w*q1.w;
        #pragma unroll
        for (int m = 1; m <= 8; m <<= 1) {
            dp += __shfl_xor(dp, m);
            qs += __shfl_xor(qs, m);
        }
        if (c == 0) { s_dot[gid + 16] = dp; s_qsq[gid + 16] = qs; }
    }
    __syncthreads();

    // ---- scores + loss terms (wave 0 only); partial -> bucket ----
    if (wave == 0) {
        const float t = 1.0f / sqrtf(t_pow);     // num^(-0.5)
        const float pos_score = t * s_dot[0] + bp;

        if (lane < NNEG) {
            float neg_score = t * s_dot[lane + 1] + bn;
            float d = 1.0f - pos_score + neg_score;
            contrib += d * d + LAMDA * bn * bn + BATA * s_qsq[lane + 1];
        }
        if (lane == 0)
            contrib += LAMDA * bp * bp + BATA * s_qsq[0];

        #pragma unroll
        for (int m = 1; m < 64; m <<= 1)
            contrib += __shfl_xor(contrib, m);

        if (lane == 0) {
            const int bk = b & (NBUCKET - 1);
            // relaxed RMW at coherent point; 64 RMWs per address, 64-way parallel
            atomicAdd((float*)(ws + bk * 64), contrib);
            // order: bucket RMW globally performed before sub-counter RMW issues
            asm volatile("s_waitcnt vmcnt(0)" ::: "memory");
            unsigned old = atomicAdd((unsigned*)(ws + WS_SUB_OFF + bk * 64), 1u);
            int won = 0;
            if (old == (NB / NBUCKET) - 1) {       // last block of this bucket
                // old's use already forced completion of the sub RMW
                unsigned so = atomicAdd((unsigned*)(ws + WS_SUPER_OFF), 1u);
                won = (so == NBUCKET - 1);          // globally last
            }
            s_won = won;
        }
    }
    __syncthreads();

    // ---- globally-last block: sum the 64 buckets in fixed order ----
    if (s_won && wave == 0) {
        float v = __hip_atomic_load((const float*)(ws + lane * 64),
                                    __ATOMIC_RELAXED, __HIP_MEMORY_SCOPE_AGENT);
        #pragma unroll
        for (int m = 1; m < 64; m <<= 1)
            v += __shfl_xor(v, m);
        if (lane == 0)
            out[0] = v;
    }
}

extern "C" void kernel_launch(void* const* d_in, const int* in_sizes, int n_in,
                              void* d_out, int out_size, void* d_ws, size_t ws_size,
                              hipStream_t stream) {
    const int*   pos_items     = (const int*)  d_in[0];
    const int*   neg_items     = (const int*)  d_in[1];
    const float* user_item_num = (const float*)d_in[2];
    const int*   interacted    = (const int*)  d_in[3];
    const float* pu            = (const float*)d_in[4];
    const float* qi            = (const float*)d_in[5];
    const float* bi            = (const float*)d_in[6];
    char*  ws  = (char*)d_ws;
    float* out = (float*)d_out;

    hipMemsetAsync(ws, 0, WS_ZERO_BYTES, stream);   // buckets + counters
    fism_kernel<<<NB, 256, 0, stream>>>(
        pos_items, neg_items, user_item_num, interacted, pu, qi, bi, ws, out);
}

// Round 8
// 38.229 us; speedup vs baseline: 6.8782x; 1.1487x over previous
//
#include <hip/hip_runtime.h>

#define NB 4096
#define HIST 200
#define NNEG 20
#define DIM 64
#define BATA 1e-4f
#define LAMDA 1e-4f

// one BLOCK (4 waves) per user; 16 (wave,group) units x 12 rows; waves 0-1
// additionally cover the 8-row tail (wave-uniform branch, no divergence).
// Partials -> d_ws, then a 1-block reduce kernel (fixed order, deterministic).
__global__ __launch_bounds__(256) void fism_kernel(
    const int* __restrict__ pos_items,
    const int* __restrict__ neg_items,
    const float* __restrict__ user_item_num,
    const int* __restrict__ interacted,
    const float* __restrict__ pu,
    const float* __restrict__ qi,
    const float* __restrict__ bi,
    float* __restrict__ partials)
{
    const int wave = threadIdx.x >> 6;   // 0..3
    const int lane = threadIdx.x & 63;
    const int g    = lane >> 4;          // row-group within wave, 0..3
    const int c    = lane & 15;          // float4 column within a 64-f32 row
    const int gid  = wave * 4 + g;       // 0..15 global group id
    const int b    = blockIdx.x;

    __shared__ float4 s_u[4][16];
    __shared__ float  s_dot[24];
    __shared__ float  s_qsq[24];

    const float4* pu4 = (const float4*)pu;
    const float4* qi4 = (const float4*)qi;
    const int*    it  = interacted + b * HIST;
    const int*    negp = neg_items + b * NNEG;

    // ---- preload: indices, qi fragments, biases ----
    const int posi = pos_items[b];

    const int4* it4 = (const int4*)(it + gid * 12);
    int4 i0 = it4[0], i1 = it4[1], i2 = it4[2];

    const int item0 = (gid == 0) ? posi : negp[gid - 1];
    float4 q0 = qi4[item0 * (DIM / 4) + c];
    float4 q1 = make_float4(0.f, 0.f, 0.f, 0.f);
    if (gid < 5) {                       // j1 = gid+16 in [16,20]
        int item1 = negp[gid + 15];
        q1 = qi4[item1 * (DIM / 4) + c];
    }

    float t_pow = 0.f, bp = 0.f, bn = 0.f;
    if (wave == 0) {
        t_pow = user_item_num[b];
        bp = bi[posi];
        if (lane < NNEG) bn = bi[negp[lane]];
    }

    // ---- user embedding: 12 independent row gathers, 2 accumulator chains --
    float4 a0 = make_float4(0.f, 0.f, 0.f, 0.f);
    float4 a1 = make_float4(0.f, 0.f, 0.f, 0.f);
    {
        float4 v0  = pu4[i0.x * (DIM / 4) + c];
        float4 v1  = pu4[i0.y * (DIM / 4) + c];
        float4 v2  = pu4[i0.z * (DIM / 4) + c];
        float4 v3  = pu4[i0.w * (DIM / 4) + c];
        float4 v4  = pu4[i1.x * (DIM / 4) + c];
        float4 v5  = pu4[i1.y * (DIM / 4) + c];
        float4 v6  = pu4[i1.z * (DIM / 4) + c];
        float4 v7  = pu4[i1.w * (DIM / 4) + c];
        float4 v8  = pu4[i2.x * (DIM / 4) + c];
        float4 v9  = pu4[i2.y * (DIM / 4) + c];
        float4 v10 = pu4[i2.z * (DIM / 4) + c];
        float4 v11 = pu4[i2.w * (DIM / 4) + c];

        a0.x += v0.x + v1.x; a0.y += v0.y + v1.y; a0.z += v0.z + v1.z; a0.w += v0.w + v1.w;
        a1.x += v2.x + v3.x; a1.y += v2.y + v3.y; a1.z += v2.z + v3.z; a1.w += v2.w + v3.w;
        a0.x += v4.x + v5.x; a0.y += v4.y + v5.y; a0.z += v4.z + v5.z; a0.w += v4.w + v5.w;
        a1.x += v6.x + v7.x; a1.y += v6.y + v7.y; a1.z += v6.z + v7.z; a1.w += v6.w + v7.w;
        a0.x += v8.x + v9.x; a0.y += v8.y + v9.y; a0.z += v8.z + v9.z; a0.w += v8.w + v9.w;
        a1.x += v10.x + v11.x; a1.y += v10.y + v11.y; a1.z += v10.z + v11.z; a1.w += v10.w + v11.w;
    }
    // tail rows 192..199: handled by waves 0-1 only (wave-uniform branch,
    // gid<8 <=> wave<2) — skips 8 redundant row-loads per user.
    if (wave < 2) {
        int  tidx = it[192 + (gid & 7)];
        float4 vt = pu4[tidx * (DIM / 4) + c];
        a0.x += vt.x; a0.y += vt.y; a0.z += vt.z; a0.w += vt.w;
    }
    float4 u = make_float4(a0.x + a1.x, a0.y + a1.y, a0.z + a1.z, a0.w + a1.w);

    // fold the 4 groups within this wave (lanes sharing c hold same dims)
    #pragma unroll
    for (int m = 16; m <= 32; m <<= 1) {
        u.x += __shfl_xor(u.x, m);
        u.y += __shfl_xor(u.y, m);
        u.z += __shfl_xor(u.z, m);
        u.w += __shfl_xor(u.w, m);
    }
    if (lane < 16) s_u[wave][lane] = u;
    __syncthreads();

    // total user embedding, dims [4c, 4c+3]
    float4 u0 = s_u[0][c], u1 = s_u[1][c], u2 = s_u[2][c], u3 = s_u[3][c];
    float4 ut = make_float4(u0.x + u1.x + u2.x + u3.x,
                            u0.y + u1.y + u2.y + u3.y,
                            u0.z + u1.z + u2.z + u3.z,
                            u0.w + u1.w + u2.w + u3.w);

    float contrib = 0.f;
    if (wave == 0 && g == 0)   // 16 lanes cover the 16 columns exactly once
        contrib += BATA * (ut.x*ut.x + ut.y*ut.y + ut.z*ut.z + ut.w*ut.w);

    // ---- dots with preloaded qi fragments ----
    {
        float dp = ut.x*q0.x + ut.y*q0.y + ut.z*q0.z + ut.w*q0.w;
        float qs = q0.x*q0.x + q0.y*q0.y + q0.z*q0.z + q0.w*q0.w;
        #pragma unroll
        for (int m = 1; m <= 8; m <<= 1) {
            dp += __shfl_xor(dp, m);
            qs += __shfl_xor(qs, m);
        }
        if (c == 0) { s_dot[gid] = dp; s_qsq[gid] = qs; }
    }
    if (gid < 5) {
        float dp = ut.x*q1.x + ut.y*q1.y + ut.z*q1.z + ut.w*q1.w;
        float qs = q1.x*q1.x + q1.y*q1.y + q1.z*q1.z + q1.w*q1.w;
        #pragma unroll
        for (int m = 1; m <= 8; m <<= 1) {
            dp += __shfl_xor(dp, m);
            qs += __shfl_xor(qs, m);
        }
        if (c == 0) { s_dot[gid + 16] = dp; s_qsq[gid + 16] = qs; }
    }
    __syncthreads();

    // ---- scores + loss terms (wave 0 only) ----
    if (wave == 0) {
        const float t = 1.0f / sqrtf(t_pow);     // num^(-0.5)
        const float pos_score = t * s_dot[0] + bp;

        if (lane < NNEG) {
            float neg_score = t * s_dot[lane + 1] + bn;
            float d = 1.0f - pos_score + neg_score;
            contrib += d * d + LAMDA * bn * bn + BATA * s_qsq[lane + 1];
        }
        if (lane == 0)
            contrib += LAMDA * bp * bp + BATA * s_qsq[0];

        #pragma unroll
        for (int m = 1; m < 64; m <<= 1)
            contrib += __shfl_xor(contrib, m);
        if (lane == 0)
            partials[b] = contrib;               // plain store, no atomic
    }
}

// single block: sum 4096 partials (float4 loads) in fixed order -> out[0]
__global__ __launch_bounds__(1024) void reduce_kernel(
    const float* __restrict__ part, float* __restrict__ out)
{
    __shared__ float s[16];
    const int t = threadIdx.x;
    float4 p = ((const float4*)part)[t];         // 1024 x float4 = 4096
    float v = (p.x + p.y) + (p.z + p.w);
    #pragma unroll
    for (int m = 1; m < 64; m <<= 1)
        v += __shfl_xor(v, m);
    if ((t & 63) == 0) s[t >> 6] = v;
    __syncthreads();
    if (t < 16) {
        float x = s[t];
        #pragma unroll
        for (int m = 1; m < 16; m <<= 1)
            x += __shfl_xor(x, m);
        if (t == 0) out[0] = x;
    }
}

extern "C" void kernel_launch(void* const* d_in, const int* in_sizes, int n_in,
                              void* d_out, int out_size, void* d_ws, size_t ws_size,
                              hipStream_t stream) {
    const int*   pos_items     = (const int*)  d_in[0];
    const int*   neg_items     = (const int*)  d_in[1];
    const float* user_item_num = (const float*)d_in[2];
    const int*   interacted    = (const int*)  d_in[3];
    const float* pu            = (const float*)d_in[4];
    const float* qi            = (const float*)d_in[5];
    const float* bi            = (const float*)d_in[6];
    float* partials = (float*)d_ws;               // 4096 floats = 16 KB
    float* out = (float*)d_out;

    fism_kernel<<<NB, 256, 0, stream>>>(
        pos_items, neg_items, user_item_num, interacted, pu, qi, bi, partials);
    reduce_kernel<<<1, 1024, 0, stream>>>(partials, out);
}